// Round 3
// baseline (972.742 us; speedup 1.0000x reference)
//
#include <hip/hip_runtime.h>
#include <hip/hip_bf16.h>

// Problem constants (match reference)
#define NN 50000
#define EE 800000
#define GG 256
#define FF 128
#define HH 64
#define CC 10
#define BN_EPS 1e-5f

__device__ __forceinline__ float lane_bcast(float v, int srcLane) {
    union { float f; int i; } u; u.f = v;
    u.i = __builtin_amdgcn_readlane(u.i, srcLane);
    return u.f;
}

// ---------------- column stats of x [N,128] -> sums[0:128]=sum, sums[128:256]=sumsq
__global__ __launch_bounds__(256) void colstats128(const float* __restrict__ x,
                                                   float* __restrict__ sums, int n) {
    const int ROWS = (NN + 255) >> 8;  // rows per block
    int col = threadIdx.x & 127;
    int rh  = threadIdx.x >> 7;  // 0 or 1
    int r0  = blockIdx.x * ROWS;
    int r1  = min(n, r0 + ROWS);
    float s = 0.f, sq = 0.f;
    for (int r = r0 + rh; r < r1; r += 2) {
        float v = x[(size_t)r * FF + col];
        s += v; sq += v * v;
    }
    __shared__ float ls[256], lq[256];
    ls[threadIdx.x] = s; lq[threadIdx.x] = sq;
    __syncthreads();
    if (threadIdx.x < 128) {
        atomicAdd(&sums[col], ls[threadIdx.x] + ls[threadIdx.x + 128]);
        atomicAdd(&sums[128 + col], lq[threadIdx.x] + lq[threadIdx.x + 128]);
    }
}

// ---------------- fold bn_feat into w_feat: Wf[j][k]=a[j]*W[j][k], bf[k]=b_feat[k]+sum_j c[j]W[j][k]
__global__ void fold_feat(const float* __restrict__ sums, const float* __restrict__ g,
                          const float* __restrict__ b, const float* __restrict__ W,
                          const float* __restrict__ bias_in, float* __restrict__ Wf,
                          float* __restrict__ bf, float invn) {
    __shared__ float a[FF], c[FF];
    int j = threadIdx.x;  // 128 threads
    float m = sums[j] * invn;
    float v = sums[FF + j] * invn - m * m;
    float aj = g[j] * rsqrtf(v + BN_EPS);
    a[j] = aj;
    c[j] = fmaf(-aj, m, b[j]);
    __syncthreads();
    for (int idx = j; idx < FF * HH; idx += FF) {
        int jj = idx >> 6;
        Wf[idx] = a[jj] * W[idx];
    }
    if (j < HH) {
        float acc = bias_in[j];
        for (int jj = 0; jj < FF; jj++) acc = fmaf(c[jj], W[jj * HH + j], acc);
        bf[j] = acc;
    }
}

// ---------------- h = relu(x @ Wf + bf)  [N,128] @ [128,64]
__global__ __launch_bounds__(256) void gemm_feat(const float* __restrict__ x,
                                                 const float* __restrict__ Wf,
                                                 const float* __restrict__ bf,
                                                 float* __restrict__ h, int n) {
    int lane = threadIdx.x & 63;
    int wid  = threadIdx.x >> 6;
    float w[FF];
#pragma unroll
    for (int j = 0; j < FF; j++) w[j] = Wf[j * HH + lane];
    float bv = bf[lane];
    int wstride = gridDim.x * 4;
    for (int r = blockIdx.x * 4 + wid; r < n; r += wstride) {
        float xa = x[(size_t)r * FF + lane];
        float xb = x[(size_t)r * FF + 64 + lane];
        float a0 = bv, a1 = 0.f, a2 = 0.f, a3 = 0.f;
#pragma unroll
        for (int j = 0; j < 64; j += 4) {
            a0 = fmaf(lane_bcast(xa, j),     w[j],     a0);
            a1 = fmaf(lane_bcast(xa, j + 1), w[j + 1], a1);
            a2 = fmaf(lane_bcast(xa, j + 2), w[j + 2], a2);
            a3 = fmaf(lane_bcast(xa, j + 3), w[j + 3], a3);
        }
#pragma unroll
        for (int j = 0; j < 64; j += 4) {
            a0 = fmaf(lane_bcast(xb, j),     w[64 + j],     a0);
            a1 = fmaf(lane_bcast(xb, j + 1), w[64 + j + 1], a1);
            a2 = fmaf(lane_bcast(xb, j + 2), w[64 + j + 2], a2);
            a3 = fmaf(lane_bcast(xb, j + 3), w[64 + j + 3], a3);
        }
        h[(size_t)r * HH + lane] = fmaxf((a0 + a1) + (a2 + a3), 0.f);
    }
}

// ---------------- CSR build
__global__ void hist_kernel(const int* __restrict__ dst, int* __restrict__ cnt, int e) {
    int i = blockIdx.x * blockDim.x + threadIdx.x;
    if (i < e) atomicAdd(&cnt[dst[i]], 1);
}

__global__ void scan50k(const int* __restrict__ cnt, int* __restrict__ rowptr, int n) {
    __shared__ int ps[257];
    int t = threadIdx.x;
    int chunk = (n + 255) >> 8;
    int lo = min(t * chunk, n), hi = min(lo + chunk, n);
    int s = 0;
    for (int i = lo; i < hi; i++) s += cnt[i];
    ps[t + 1] = s;
    __syncthreads();
    if (t == 0) {
        ps[0] = 0;
        for (int i = 1; i <= 256; i++) ps[i] += ps[i - 1];
    }
    __syncthreads();
    int run = ps[t];
    for (int i = lo; i < hi; i++) { rowptr[i] = run; run += cnt[i]; }
    if (t == 255) rowptr[n] = run;
}

__global__ void fill_csr(const int* __restrict__ src, const int* __restrict__ dst,
                         const int* __restrict__ rowptr, int* __restrict__ cursor,
                         int* __restrict__ csr, int e) {
    int i = blockIdx.x * blockDim.x + threadIdx.x;
    if (i < e) {
        int d = dst[i];
        int slot = rowptr[d] + atomicAdd(&cursor[d], 1);
        csr[slot] = src[i];
    }
}

// ---------------- z[n] = h[n] + sum_{e in CSR[n]} h[csr_src[e]]
__global__ __launch_bounds__(256) void aggregate(const float* __restrict__ hin,
                                                 const int* __restrict__ rowptr,
                                                 const int* __restrict__ csr,
                                                 float* __restrict__ z, int n) {
    int lane = threadIdx.x & 63;
    int wid  = threadIdx.x >> 6;
    int wstride = gridDim.x * 4;
    for (int node = blockIdx.x * 4 + wid; node < n; node += wstride) {
        int lo = rowptr[node], hi = rowptr[node + 1];
        float acc = hin[(size_t)node * HH + lane];
        for (int base = lo; base < hi; base += 64) {
            int m = min(64, hi - base);
            int eid = (lane < m) ? csr[base + lane] : 0;
            for (int t = 0; t < m; t++) {
                int s = __shfl(eid, t);
                acc += hin[(size_t)s * HH + lane];
            }
        }
        z[(size_t)node * HH + lane] = acc;
    }
}

// ---------------- y = z @ W1 + b1 (in-place), accumulate column sum/sumsq
__global__ __launch_bounds__(256) void gin_lin1(float* __restrict__ zy,
                                                const float* __restrict__ W,
                                                const float* __restrict__ bias,
                                                float* __restrict__ stats, int n) {
    int lane = threadIdx.x & 63;
    int wid  = threadIdx.x >> 6;
    float w[HH];
#pragma unroll
    for (int j = 0; j < HH; j++) w[j] = W[j * HH + lane];
    float bv = bias[lane];
    float s = 0.f, sq = 0.f;
    int wstride = gridDim.x * 4;
    for (int r = blockIdx.x * 4 + wid; r < n; r += wstride) {
        float zv = zy[(size_t)r * HH + lane];
        float a0 = bv, a1 = 0.f;
#pragma unroll
        for (int j = 0; j < HH; j += 2) {
            a0 = fmaf(lane_bcast(zv, j),     w[j],     a0);
            a1 = fmaf(lane_bcast(zv, j + 1), w[j + 1], a1);
        }
        float acc = a0 + a1;
        zy[(size_t)r * HH + lane] = acc;
        s += acc; sq += acc * acc;
    }
    atomicAdd(&stats[lane], s);
    atomicAdd(&stats[HH + lane], sq);
}

// ---------------- a,c from stats
__global__ void bn_params(const float* __restrict__ stats, const float* __restrict__ g,
                          const float* __restrict__ b, float* __restrict__ ac,
                          float invn, int cols) {
    int k = threadIdx.x;
    if (k < cols) {
        float m = stats[k] * invn;
        float v = stats[cols + k] * invn - m * m;
        float a = g[k] * rsqrtf(v + BN_EPS);
        ac[k] = a;
        ac[cols + k] = fmaf(-a, m, b[k]);
    }
}

// ---------------- h = relu( relu(a*y+c) @ W2 + b2 ) (in-place)
__global__ __launch_bounds__(256) void gin_lin2(float* __restrict__ yh,
                                                const float* __restrict__ ac,
                                                const float* __restrict__ W2,
                                                const float* __restrict__ b2, int n) {
    int lane = threadIdx.x & 63;
    int wid  = threadIdx.x >> 6;
    float w[HH];
#pragma unroll
    for (int j = 0; j < HH; j++) w[j] = W2[j * HH + lane];
    float a = ac[lane], c = ac[HH + lane];
    float bv = b2[lane];
    int wstride = gridDim.x * 4;
    for (int r = blockIdx.x * 4 + wid; r < n; r += wstride) {
        float yv = yh[(size_t)r * HH + lane];
        float zv = fmaxf(fmaf(a, yv, c), 0.f);
        float a0 = bv, a1 = 0.f;
#pragma unroll
        for (int j = 0; j < HH; j += 2) {
            a0 = fmaf(lane_bcast(zv, j),     w[j],     a0);
            a1 = fmaf(lane_bcast(zv, j + 1), w[j + 1], a1);
        }
        yh[(size_t)r * HH + lane] = fmaxf(a0 + a1, 0.f);
    }
}

// ---------------- global_add_pool: batch is sorted; block per graph, binary search bounds
__global__ __launch_bounds__(64) void pool_kernel(const float* __restrict__ h,
                                                  const int* __restrict__ batch,
                                                  float* __restrict__ hg, int n) {
    int g = blockIdx.x;
    int lo = 0, hi = n;
    while (lo < hi) { int mid = (lo + hi) >> 1; if (batch[mid] < g) lo = mid + 1; else hi = mid; }
    int start = lo;
    lo = start; hi = n;
    while (lo < hi) { int mid = (lo + hi) >> 1; if (batch[mid] < g + 1) lo = mid + 1; else hi = mid; }
    int end = lo;
    int lane = threadIdx.x;
    float acc = 0.f;
    for (int r = start; r < end; r++) acc += h[(size_t)r * HH + lane];
    hg[g * HH + lane] = acc;
}

// ---------------- head part 1: hh = relu(bn(hg) @ lin_w + lin_b), single block
__global__ __launch_bounds__(256) void head1(const float* __restrict__ hg,
                                             const float* __restrict__ g,
                                             const float* __restrict__ b,
                                             const float* __restrict__ lw,
                                             const float* __restrict__ lb,
                                             float* __restrict__ hh) {
    __shared__ float Wt[HH * HH];  // transposed: Wt[k][j] = lw[j][k]
    __shared__ float s1[256], s2[256];
    __shared__ float aa[HH], cc[HH];
    int t = threadIdx.x;
    for (int i = t; i < HH * HH; i += 256) {
        int j = i >> 6, k = i & 63;
        Wt[k * HH + j] = lw[i];
    }
    int col = t & 63, q = t >> 6;
    float s = 0.f, sq = 0.f;
    for (int r = q; r < GG; r += 4) { float v = hg[r * HH + col]; s += v; sq += v * v; }
    s1[t] = s; s2[t] = sq;
    __syncthreads();
    if (t < HH) {
        float S = s1[t] + s1[t + 64] + s1[t + 128] + s1[t + 192];
        float Q = s2[t] + s2[t + 64] + s2[t + 128] + s2[t + 192];
        float m = S * (1.f / GG), v = Q * (1.f / GG) - m * m;
        float a = g[t] * rsqrtf(v + BN_EPS);
        aa[t] = a; cc[t] = fmaf(-a, m, b[t]);
    }
    __syncthreads();
    float rv[HH];
#pragma unroll
    for (int j = 0; j < HH; j++) rv[j] = fmaf(aa[j], hg[t * HH + j], cc[j]);
#pragma unroll 4
    for (int k = 0; k < HH; k++) {
        float acc = lb[k];
#pragma unroll
        for (int j = 0; j < HH; j++) acc = fmaf(rv[j], Wt[k * HH + j], acc);
        hh[t * HH + k] = fmaxf(acc, 0.f);
    }
}

// ---------------- head part 2: out = bn(hh) @ cls_w + cls_b, single block
__global__ __launch_bounds__(256) void head2(const float* __restrict__ hh,
                                             const float* __restrict__ g,
                                             const float* __restrict__ b,
                                             const float* __restrict__ cw,
                                             const float* __restrict__ cb,
                                             float* __restrict__ out) {
    __shared__ float s1[256], s2[256];
    __shared__ float aa[HH], cc[HH];
    __shared__ float Wc[HH * CC];
    __shared__ float cbs[CC];
    int t = threadIdx.x;
    for (int i = t; i < HH * CC; i += 256) Wc[i] = cw[i];
    if (t < CC) cbs[t] = cb[t];
    int col = t & 63, q = t >> 6;
    float s = 0.f, sq = 0.f;
    for (int r = q; r < GG; r += 4) { float v = hh[r * HH + col]; s += v; sq += v * v; }
    s1[t] = s; s2[t] = sq;
    __syncthreads();
    if (t < HH) {
        float S = s1[t] + s1[t + 64] + s1[t + 128] + s1[t + 192];
        float Q = s2[t] + s2[t + 64] + s2[t + 128] + s2[t + 192];
        float m = S * (1.f / GG), v = Q * (1.f / GG) - m * m;
        float a = g[t] * rsqrtf(v + BN_EPS);
        aa[t] = a; cc[t] = fmaf(-a, m, b[t]);
    }
    __syncthreads();
    float acc[CC];
#pragma unroll
    for (int c2 = 0; c2 < CC; c2++) acc[c2] = cbs[c2];
#pragma unroll
    for (int j = 0; j < HH; j++) {
        float v = fmaf(aa[j], hh[t * HH + j], cc[j]);
#pragma unroll
        for (int c2 = 0; c2 < CC; c2++) acc[c2] = fmaf(v, Wc[j * CC + c2], acc[c2]);
    }
#pragma unroll
    for (int c2 = 0; c2 < CC; c2++) out[t * CC + c2] = acc[c2];
}

extern "C" void kernel_launch(void* const* d_in, const int* in_sizes, int n_in,
                              void* d_out, int out_size, void* d_ws, size_t ws_size,
                              hipStream_t stream) {
    const float* x        = (const float*)d_in[0];
    const int*   ei       = (const int*)d_in[1];
    const int*   srcp     = ei;
    const int*   dstp     = ei + EE;
    const int*   batchp   = (const int*)d_in[2];
    const float* bnf_g    = (const float*)d_in[3];
    const float* bnf_b    = (const float*)d_in[4];
    const float* w_feat   = (const float*)d_in[5];
    const float* b_feat   = (const float*)d_in[6];
    const float* gin_w1   = (const float*)d_in[7];
    const float* gin_b1   = (const float*)d_in[8];
    const float* gin_bn_g = (const float*)d_in[9];
    const float* gin_bn_b = (const float*)d_in[10];
    const float* gin_w2   = (const float*)d_in[11];
    const float* gin_b2   = (const float*)d_in[12];
    const float* bn_fc_g  = (const float*)d_in[13];
    const float* bn_fc_b  = (const float*)d_in[14];
    const float* lin_w    = (const float*)d_in[15];
    const float* lin_b    = (const float*)d_in[16];
    const float* bn_h_g   = (const float*)d_in[17];
    const float* bn_h_b   = (const float*)d_in[18];
    const float* cls_w    = (const float*)d_in[19];
    const float* cls_b    = (const float*)d_in[20];
    float* out = (float*)d_out;

    // workspace layout (floats, then ints)
    float* ws   = (float*)d_ws;
    float* bufA = ws;                     // N*H
    float* bufB = bufA + (size_t)NN * HH; // N*H
    float* Wf   = bufB + (size_t)NN * HH; // F*H
    float* bff  = Wf + FF * HH;           // H
    float* stats= bff + HH;               // 2*F (also reused as 2*H)
    float* ac   = stats + 2 * FF;         // 2*H
    float* hh   = ac + 2 * HH;            // G*H
    float* hg   = hh + GG * HH;           // G*H
    int* rowptr = (int*)(hg + GG * HH);   // N+1
    int* cnt    = rowptr + (NN + 1);      // N
    int* csr    = cnt + NN;               // E

    // --- bn_feat folded into linear, then h0 = relu(x @ Wf + bf)
    hipMemsetAsync(stats, 0, 2 * FF * sizeof(float), stream);
    colstats128<<<256, 256, 0, stream>>>(x, stats, NN);
    fold_feat<<<1, 128, 0, stream>>>(stats, bnf_g, bnf_b, w_feat, b_feat, Wf, bff, 1.0f / NN);
    gemm_feat<<<512, 256, 0, stream>>>(x, Wf, bff, bufA, NN);

    // --- CSR build (reused by all 3 GIN layers)
    hipMemsetAsync(cnt, 0, NN * sizeof(int), stream);
    hist_kernel<<<(EE + 255) / 256, 256, 0, stream>>>(dstp, cnt, EE);
    scan50k<<<1, 256, 0, stream>>>(cnt, rowptr, NN);
    hipMemsetAsync(cnt, 0, NN * sizeof(int), stream);
    fill_csr<<<(EE + 255) / 256, 256, 0, stream>>>(srcp, dstp, rowptr, cnt, csr, EE);

    // --- 3 GIN layers, ping-pong bufA/bufB
    float* hin = bufA;
    float* hout = bufB;
    for (int i = 0; i < 3; i++) {
        aggregate<<<1024, 256, 0, stream>>>(hin, rowptr, csr, hout, NN);
        hipMemsetAsync(stats, 0, 2 * HH * sizeof(float), stream);
        gin_lin1<<<512, 256, 0, stream>>>(hout, gin_w1 + i * HH * HH, gin_b1 + i * HH, stats, NN);
        bn_params<<<1, 64, 0, stream>>>(stats, gin_bn_g + i * HH, gin_bn_b + i * HH, ac, 1.0f / NN, HH);
        gin_lin2<<<512, 256, 0, stream>>>(hout, ac, gin_w2 + i * HH * HH, gin_b2 + i * HH, NN);
        float* tmp = hin; hin = hout; hout = tmp;
    }
    // final h is in hin

    // --- pool + head
    pool_kernel<<<GG, 64, 0, stream>>>(hin, batchp, hg, NN);
    head1<<<1, 256, 0, stream>>>(hg, bn_fc_g, bn_fc_b, lin_w, lin_b, hh);
    head2<<<1, 256, 0, stream>>>(hh, bn_h_g, bn_h_b, cls_w, cls_b, out);
}

// Round 5
// 899.084 us; speedup vs baseline: 1.0819x; 1.0819x over previous
//
#include <hip/hip_runtime.h>
#include <hip/hip_bf16.h>

// Problem constants (match reference)
#define NN 50000
#define EE 800000
#define GG 256
#define FF 128
#define HH 64
#define CC 10
#define BN_EPS 1e-5f
#define NB_SCAN ((NN + 255) / 256)   // 196 tiles for the prefix scan

__device__ __forceinline__ float lane_bcast(float v, int srcLane) {
    union { float f; int i; } u; u.f = v;
    u.i = __builtin_amdgcn_readlane(u.i, srcLane);
    return u.f;
}

// ---------------- column stats of x [N,128] -> sums[0:128]=sum, sums[128:256]=sumsq
__global__ __launch_bounds__(256) void colstats128(const float* __restrict__ x,
                                                   float* __restrict__ sums, int n) {
    const int ROWS = (NN + 255) >> 8;  // rows per block
    int col = threadIdx.x & 127;
    int rh  = threadIdx.x >> 7;  // 0 or 1
    int r0  = blockIdx.x * ROWS;
    int r1  = min(n, r0 + ROWS);
    float s = 0.f, sq = 0.f;
    for (int r = r0 + rh; r < r1; r += 2) {
        float v = x[(size_t)r * FF + col];
        s += v; sq += v * v;
    }
    __shared__ float ls[256], lq[256];
    ls[threadIdx.x] = s; lq[threadIdx.x] = sq;
    __syncthreads();
    if (threadIdx.x < 128) {
        atomicAdd(&sums[col], ls[threadIdx.x] + ls[threadIdx.x + 128]);
        atomicAdd(&sums[128 + col], lq[threadIdx.x] + lq[threadIdx.x + 128]);
    }
}

// ---------------- fold bn_feat into w_feat: Wf[j][k]=a[j]*W[j][k], bf[k]=b_feat[k]+sum_j c[j]W[j][k]
__global__ void fold_feat(const float* __restrict__ sums, const float* __restrict__ g,
                          const float* __restrict__ b, const float* __restrict__ W,
                          const float* __restrict__ bias_in, float* __restrict__ Wf,
                          float* __restrict__ bf, float invn) {
    __shared__ float a[FF], c[FF];
    int j = threadIdx.x;  // 128 threads
    float m = sums[j] * invn;
    float v = sums[FF + j] * invn - m * m;
    float aj = g[j] * rsqrtf(v + BN_EPS);
    a[j] = aj;
    c[j] = fmaf(-aj, m, b[j]);
    __syncthreads();
    for (int idx = j; idx < FF * HH; idx += FF) {
        int jj = idx >> 6;
        Wf[idx] = a[jj] * W[idx];
    }
    if (j < HH) {
        float acc = bias_in[j];
        for (int jj = 0; jj < FF; jj++) acc = fmaf(c[jj], W[jj * HH + j], acc);
        bf[j] = acc;
    }
}

// ---------------- h = relu(x @ Wf + bf)  [N,128] @ [128,64]
__global__ __launch_bounds__(256) void gemm_feat(const float* __restrict__ x,
                                                 const float* __restrict__ Wf,
                                                 const float* __restrict__ bf,
                                                 float* __restrict__ h, int n) {
    int lane = threadIdx.x & 63;
    int wid  = threadIdx.x >> 6;
    float w[FF];
#pragma unroll
    for (int j = 0; j < FF; j++) w[j] = Wf[j * HH + lane];
    float bv = bf[lane];
    int wstride = gridDim.x * 4;
    for (int r = blockIdx.x * 4 + wid; r < n; r += wstride) {
        float xa = x[(size_t)r * FF + lane];
        float xb = x[(size_t)r * FF + 64 + lane];
        float a0 = bv, a1 = 0.f, a2 = 0.f, a3 = 0.f;
#pragma unroll
        for (int j = 0; j < 64; j += 4) {
            a0 = fmaf(lane_bcast(xa, j),     w[j],     a0);
            a1 = fmaf(lane_bcast(xa, j + 1), w[j + 1], a1);
            a2 = fmaf(lane_bcast(xa, j + 2), w[j + 2], a2);
            a3 = fmaf(lane_bcast(xa, j + 3), w[j + 3], a3);
        }
#pragma unroll
        for (int j = 0; j < 64; j += 4) {
            a0 = fmaf(lane_bcast(xb, j),     w[64 + j],     a0);
            a1 = fmaf(lane_bcast(xb, j + 1), w[64 + j + 1], a1);
            a2 = fmaf(lane_bcast(xb, j + 2), w[64 + j + 2], a2);
            a3 = fmaf(lane_bcast(xb, j + 3), w[64 + j + 3], a3);
        }
        h[(size_t)r * HH + lane] = fmaxf((a0 + a1) + (a2 + a3), 0.f);
    }
}

// ---------------- CSR build
__global__ void hist_kernel(const int* __restrict__ dst, int* __restrict__ cnt, int e) {
    int i = blockIdx.x * blockDim.x + threadIdx.x;
    if (i < e) atomicAdd(&cnt[dst[i]], 1);
}

// --- parallel scan, 3 kernels (replaces single-block scan50k: 88.9us -> ~5us) ---
// A: per-tile (256 elems) sums, coalesced
__global__ __launch_bounds__(256) void tile_sums(const int* __restrict__ cnt,
                                                 int* __restrict__ bsum, int n) {
    __shared__ int red[256];
    int i = blockIdx.x * 256 + threadIdx.x;
    red[threadIdx.x] = (i < n) ? cnt[i] : 0;
    __syncthreads();
    for (int off = 128; off > 0; off >>= 1) {
        if (threadIdx.x < off) red[threadIdx.x] += red[threadIdx.x + off];
        __syncthreads();
    }
    if (threadIdx.x == 0) bsum[blockIdx.x] = red[0];
}

// B: exclusive scan of the <=256 tile sums (single tiny block)
__global__ __launch_bounds__(256) void scan_bsums(int* __restrict__ bsum, int nb) {
    __shared__ int s[256];
    int t = threadIdx.x;
    int v = (t < nb) ? bsum[t] : 0;
    s[t] = v;
    __syncthreads();
    for (int off = 1; off < 256; off <<= 1) {
        int x = (t >= off) ? s[t - off] : 0;
        __syncthreads();
        s[t] += x;
        __syncthreads();
    }
    if (t < nb) bsum[t] = s[t] - v;  // exclusive
}

// C: per-tile exclusive scan + tile offset -> rowptr, coalesced
__global__ __launch_bounds__(256) void scan_tiles_write(const int* __restrict__ cnt,
                                                        const int* __restrict__ bscan,
                                                        int* __restrict__ rowptr, int n) {
    __shared__ int s[256];
    int b = blockIdx.x, t = threadIdx.x;
    int i = b * 256 + t;
    int v = (i < n) ? cnt[i] : 0;
    s[t] = v;
    __syncthreads();
    for (int off = 1; off < 256; off <<= 1) {
        int x = (t >= off) ? s[t - off] : 0;
        __syncthreads();
        s[t] += x;
        __syncthreads();
    }
    if (i < n) rowptr[i] = bscan[b] + s[t] - v;
    if (b == 0 && t == 0) rowptr[n] = EE;  // all edges land in [0,N)
}

__global__ void fill_csr(const int* __restrict__ src, const int* __restrict__ dst,
                         const int* __restrict__ rowptr, int* __restrict__ cursor,
                         int* __restrict__ csr, int e) {
    int i = blockIdx.x * blockDim.x + threadIdx.x;
    if (i < e) {
        int d = dst[i];
        int slot = rowptr[d] + atomicAdd(&cursor[d], 1);
        csr[slot] = src[i];
    }
}

// ---------------- z[n] = h[n] + sum_{e in CSR[n]} h[csr_src[e]]
__global__ __launch_bounds__(256) void aggregate(const float* __restrict__ hin,
                                                 const int* __restrict__ rowptr,
                                                 const int* __restrict__ csr,
                                                 float* __restrict__ z, int n) {
    int lane = threadIdx.x & 63;
    int wid  = threadIdx.x >> 6;
    int wstride = gridDim.x * 4;
    for (int node = blockIdx.x * 4 + wid; node < n; node += wstride) {
        int lo = rowptr[node], hi = rowptr[node + 1];
        float acc = hin[(size_t)node * HH + lane];
        for (int base = lo; base < hi; base += 64) {
            int m = min(64, hi - base);
            int eid = (lane < m) ? csr[base + lane] : 0;
            for (int t = 0; t < m; t++) {
                int s = __shfl(eid, t);
                acc += hin[(size_t)s * HH + lane];
            }
        }
        z[(size_t)node * HH + lane] = acc;
    }
}

// ---------------- y = z @ W1 + b1 (in-place), accumulate column sum/sumsq
__global__ __launch_bounds__(256) void gin_lin1(float* __restrict__ zy,
                                                const float* __restrict__ W,
                                                const float* __restrict__ bias,
                                                float* __restrict__ stats, int n) {
    int lane = threadIdx.x & 63;
    int wid  = threadIdx.x >> 6;
    float w[HH];
#pragma unroll
    for (int j = 0; j < HH; j++) w[j] = W[j * HH + lane];
    float bv = bias[lane];
    float s = 0.f, sq = 0.f;
    int wstride = gridDim.x * 4;
    for (int r = blockIdx.x * 4 + wid; r < n; r += wstride) {
        float zv = zy[(size_t)r * HH + lane];
        float a0 = bv, a1 = 0.f;
#pragma unroll
        for (int j = 0; j < HH; j += 2) {
            a0 = fmaf(lane_bcast(zv, j),     w[j],     a0);
            a1 = fmaf(lane_bcast(zv, j + 1), w[j + 1], a1);
        }
        float acc = a0 + a1;
        zy[(size_t)r * HH + lane] = acc;
        s += acc; sq += acc * acc;
    }
    atomicAdd(&stats[lane], s);
    atomicAdd(&stats[HH + lane], sq);
}

// ---------------- a,c from stats
__global__ void bn_params(const float* __restrict__ stats, const float* __restrict__ g,
                          const float* __restrict__ b, float* __restrict__ ac,
                          float invn, int cols) {
    int k = threadIdx.x;
    if (k < cols) {
        float m = stats[k] * invn;
        float v = stats[cols + k] * invn - m * m;
        float a = g[k] * rsqrtf(v + BN_EPS);
        ac[k] = a;
        ac[cols + k] = fmaf(-a, m, b[k]);
    }
}

// ---------------- h = relu( relu(a*y+c) @ W2 + b2 ) (in-place)
__global__ __launch_bounds__(256) void gin_lin2(float* __restrict__ yh,
                                                const float* __restrict__ ac,
                                                const float* __restrict__ W2,
                                                const float* __restrict__ b2, int n) {
    int lane = threadIdx.x & 63;
    int wid  = threadIdx.x >> 6;
    float w[HH];
#pragma unroll
    for (int j = 0; j < HH; j++) w[j] = W2[j * HH + lane];
    float a = ac[lane], c = ac[HH + lane];
    float bv = b2[lane];
    int wstride = gridDim.x * 4;
    for (int r = blockIdx.x * 4 + wid; r < n; r += wstride) {
        float yv = yh[(size_t)r * HH + lane];
        float zv = fmaxf(fmaf(a, yv, c), 0.f);
        float a0 = bv, a1 = 0.f;
#pragma unroll
        for (int j = 0; j < HH; j += 2) {
            a0 = fmaf(lane_bcast(zv, j),     w[j],     a0);
            a1 = fmaf(lane_bcast(zv, j + 1), w[j + 1], a1);
        }
        yh[(size_t)r * HH + lane] = fmaxf(a0 + a1, 0.f);
    }
}

// ---------------- global_add_pool: batch is sorted; block per graph, binary search bounds
__global__ __launch_bounds__(64) void pool_kernel(const float* __restrict__ h,
                                                  const int* __restrict__ batch,
                                                  float* __restrict__ hg, int n) {
    int g = blockIdx.x;
    int lo = 0, hi = n;
    while (lo < hi) { int mid = (lo + hi) >> 1; if (batch[mid] < g) lo = mid + 1; else hi = mid; }
    int start = lo;
    lo = start; hi = n;
    while (lo < hi) { int mid = (lo + hi) >> 1; if (batch[mid] < g + 1) lo = mid + 1; else hi = mid; }
    int end = lo;
    int lane = threadIdx.x;
    float acc = 0.f;
    for (int r = start; r < end; r++) acc += h[(size_t)r * HH + lane];
    hg[g * HH + lane] = acc;
}

// ---------------- head part 1: hh = relu(bn(hg) @ lin_w + lin_b), single block
__global__ __launch_bounds__(256) void head1(const float* __restrict__ hg,
                                             const float* __restrict__ g,
                                             const float* __restrict__ b,
                                             const float* __restrict__ lw,
                                             const float* __restrict__ lb,
                                             float* __restrict__ hh) {
    __shared__ float Wt[HH * HH];  // transposed: Wt[k][j] = lw[j][k]
    __shared__ float s1[256], s2[256];
    __shared__ float aa[HH], cc[HH];
    int t = threadIdx.x;
    for (int i = t; i < HH * HH; i += 256) {
        int j = i >> 6, k = i & 63;
        Wt[k * HH + j] = lw[i];
    }
    int col = t & 63, q = t >> 6;
    float s = 0.f, sq = 0.f;
    for (int r = q; r < GG; r += 4) { float v = hg[r * HH + col]; s += v; sq += v * v; }
    s1[t] = s; s2[t] = sq;
    __syncthreads();
    if (t < HH) {
        float S = s1[t] + s1[t + 64] + s1[t + 128] + s1[t + 192];
        float Q = s2[t] + s2[t + 64] + s2[t + 128] + s2[t + 192];
        float m = S * (1.f / GG), v = Q * (1.f / GG) - m * m;
        float a = g[t] * rsqrtf(v + BN_EPS);
        aa[t] = a; cc[t] = fmaf(-a, m, b[t]);
    }
    __syncthreads();
    float rv[HH];
#pragma unroll
    for (int j = 0; j < HH; j++) rv[j] = fmaf(aa[j], hg[t * HH + j], cc[j]);
#pragma unroll 4
    for (int k = 0; k < HH; k++) {
        float acc = lb[k];
#pragma unroll
        for (int j = 0; j < HH; j++) acc = fmaf(rv[j], Wt[k * HH + j], acc);
        hh[t * HH + k] = fmaxf(acc, 0.f);
    }
}

// ---------------- head part 2: out = bn(hh) @ cls_w + cls_b, single block
__global__ __launch_bounds__(256) void head2(const float* __restrict__ hh,
                                             const float* __restrict__ g,
                                             const float* __restrict__ b,
                                             const float* __restrict__ cw,
                                             const float* __restrict__ cb,
                                             float* __restrict__ out) {
    __shared__ float s1[256], s2[256];
    __shared__ float aa[HH], cc[HH];
    __shared__ float Wc[HH * CC];
    __shared__ float cbs[CC];
    int t = threadIdx.x;
    for (int i = t; i < HH * CC; i += 256) Wc[i] = cw[i];
    if (t < CC) cbs[t] = cb[t];
    int col = t & 63, q = t >> 6;
    float s = 0.f, sq = 0.f;
    for (int r = q; r < GG; r += 4) { float v = hh[r * HH + col]; s += v; sq += v * v; }
    s1[t] = s; s2[t] = sq;
    __syncthreads();
    if (t < HH) {
        float S = s1[t] + s1[t + 64] + s1[t + 128] + s1[t + 192];
        float Q = s2[t] + s2[t + 64] + s2[t + 128] + s2[t + 192];
        float m = S * (1.f / GG), v = Q * (1.f / GG) - m * m;
        float a = g[t] * rsqrtf(v + BN_EPS);
        aa[t] = a; cc[t] = fmaf(-a, m, b[t]);
    }
    __syncthreads();
    float acc[CC];
#pragma unroll
    for (int c2 = 0; c2 < CC; c2++) acc[c2] = cbs[c2];
#pragma unroll
    for (int j = 0; j < HH; j++) {
        float v = fmaf(aa[j], hh[t * HH + j], cc[j]);
#pragma unroll
        for (int c2 = 0; c2 < CC; c2++) acc[c2] = fmaf(v, Wc[j * CC + c2], acc[c2]);
    }
#pragma unroll
    for (int c2 = 0; c2 < CC; c2++) out[t * CC + c2] = acc[c2];
}

extern "C" void kernel_launch(void* const* d_in, const int* in_sizes, int n_in,
                              void* d_out, int out_size, void* d_ws, size_t ws_size,
                              hipStream_t stream) {
    const float* x        = (const float*)d_in[0];
    const int*   ei       = (const int*)d_in[1];
    const int*   srcp     = ei;
    const int*   dstp     = ei + EE;
    const int*   batchp   = (const int*)d_in[2];
    const float* bnf_g    = (const float*)d_in[3];
    const float* bnf_b    = (const float*)d_in[4];
    const float* w_feat   = (const float*)d_in[5];
    const float* b_feat   = (const float*)d_in[6];
    const float* gin_w1   = (const float*)d_in[7];
    const float* gin_b1   = (const float*)d_in[8];
    const float* gin_bn_g = (const float*)d_in[9];
    const float* gin_bn_b = (const float*)d_in[10];
    const float* gin_w2   = (const float*)d_in[11];
    const float* gin_b2   = (const float*)d_in[12];
    const float* bn_fc_g  = (const float*)d_in[13];
    const float* bn_fc_b  = (const float*)d_in[14];
    const float* lin_w    = (const float*)d_in[15];
    const float* lin_b    = (const float*)d_in[16];
    const float* bn_h_g   = (const float*)d_in[17];
    const float* bn_h_b   = (const float*)d_in[18];
    const float* cls_w    = (const float*)d_in[19];
    const float* cls_b    = (const float*)d_in[20];
    float* out = (float*)d_out;

    // workspace layout (floats, then ints)
    float* ws   = (float*)d_ws;
    float* bufA = ws;                     // N*H
    float* bufB = bufA + (size_t)NN * HH; // N*H
    float* Wf   = bufB + (size_t)NN * HH; // F*H
    float* bff  = Wf + FF * HH;           // H
    float* stats= bff + HH;               // 2*F (also reused as 2*H)
    float* ac   = stats + 2 * FF;         // 2*H
    float* hh   = ac + 2 * HH;            // G*H
    float* hg   = hh + GG * HH;           // G*H
    int* rowptr = (int*)(hg + GG * HH);   // N+1
    int* cnt    = rowptr + (NN + 1);      // N
    int* bsum   = cnt + NN;               // NB_SCAN (tile sums for scan)
    int* csr    = bsum + NB_SCAN;         // E

    // --- bn_feat folded into linear, then h0 = relu(x @ Wf + bf)
    hipMemsetAsync(stats, 0, 2 * FF * sizeof(float), stream);
    colstats128<<<256, 256, 0, stream>>>(x, stats, NN);
    fold_feat<<<1, 128, 0, stream>>>(stats, bnf_g, bnf_b, w_feat, b_feat, Wf, bff, 1.0f / NN);
    gemm_feat<<<512, 256, 0, stream>>>(x, Wf, bff, bufA, NN);

    // --- CSR build (reused by all 3 GIN layers)
    hipMemsetAsync(cnt, 0, NN * sizeof(int), stream);
    hist_kernel<<<(EE + 255) / 256, 256, 0, stream>>>(dstp, cnt, EE);
    tile_sums<<<NB_SCAN, 256, 0, stream>>>(cnt, bsum, NN);
    scan_bsums<<<1, 256, 0, stream>>>(bsum, NB_SCAN);
    scan_tiles_write<<<NB_SCAN, 256, 0, stream>>>(cnt, bsum, rowptr, NN);
    hipMemsetAsync(cnt, 0, NN * sizeof(int), stream);
    fill_csr<<<(EE + 255) / 256, 256, 0, stream>>>(srcp, dstp, rowptr, cnt, csr, EE);

    // --- 3 GIN layers, ping-pong bufA/bufB
    float* hin = bufA;
    float* hout = bufB;
    for (int i = 0; i < 3; i++) {
        aggregate<<<1024, 256, 0, stream>>>(hin, rowptr, csr, hout, NN);
        hipMemsetAsync(stats, 0, 2 * HH * sizeof(float), stream);
        gin_lin1<<<512, 256, 0, stream>>>(hout, gin_w1 + i * HH * HH, gin_b1 + i * HH, stats, NN);
        bn_params<<<1, 64, 0, stream>>>(stats, gin_bn_g + i * HH, gin_bn_b + i * HH, ac, 1.0f / NN, HH);
        gin_lin2<<<512, 256, 0, stream>>>(hout, ac, gin_w2 + i * HH * HH, gin_b2 + i * HH, NN);
        float* tmp = hin; hin = hout; hout = tmp;
    }
    // final h is in hin

    // --- pool + head
    pool_kernel<<<GG, 64, 0, stream>>>(hin, batchp, hg, NN);
    head1<<<1, 256, 0, stream>>>(hg, bn_fc_g, bn_fc_b, lin_w, lin_b, hh);
    head2<<<1, 256, 0, stream>>>(hh, bn_h_g, bn_h_b, cls_w, cls_b, out);
}

// Round 6
// 733.262 us; speedup vs baseline: 1.3266x; 1.2261x over previous
//
#include <hip/hip_runtime.h>
#include <hip/hip_bf16.h>

// Problem constants (match reference)
#define NN 50000
#define EE 800000
#define GG 256
#define FF 128
#define HH 64
#define CC 10
#define BN_EPS 1e-5f
#define NB_SCAN ((NN + 255) / 256)   // 196 tiles for the prefix scan

__device__ __forceinline__ float lane_bcast(float v, int srcLane) {
    union { float f; int i; } u; u.f = v;
    u.i = __builtin_amdgcn_readlane(u.i, srcLane);
    return u.f;
}

// ---------------- column stats of x [N,128] -> sums[0:128]=sum, sums[128:256]=sumsq
__global__ __launch_bounds__(256) void colstats128(const float* __restrict__ x,
                                                   float* __restrict__ sums, int n) {
    const int ROWS = (NN + 255) >> 8;  // rows per block
    int col = threadIdx.x & 127;
    int rh  = threadIdx.x >> 7;  // 0 or 1
    int r0  = blockIdx.x * ROWS;
    int r1  = min(n, r0 + ROWS);
    float s = 0.f, sq = 0.f;
    for (int r = r0 + rh; r < r1; r += 2) {
        float v = x[(size_t)r * FF + col];
        s += v; sq += v * v;
    }
    __shared__ float ls[256], lq[256];
    ls[threadIdx.x] = s; lq[threadIdx.x] = sq;
    __syncthreads();
    if (threadIdx.x < 128) {
        atomicAdd(&sums[col], ls[threadIdx.x] + ls[threadIdx.x + 128]);
        atomicAdd(&sums[128 + col], lq[threadIdx.x] + lq[threadIdx.x + 128]);
    }
}

// ---------------- fold bn_feat into w_feat: Wf[j][k]=a[j]*W[j][k], bf[k]=b_feat[k]+sum_j c[j]W[j][k]
__global__ void fold_feat(const float* __restrict__ sums, const float* __restrict__ g,
                          const float* __restrict__ b, const float* __restrict__ W,
                          const float* __restrict__ bias_in, float* __restrict__ Wf,
                          float* __restrict__ bf, float invn) {
    __shared__ float a[FF], c[FF];
    int j = threadIdx.x;  // 128 threads
    float m = sums[j] * invn;
    float v = sums[FF + j] * invn - m * m;
    float aj = g[j] * rsqrtf(v + BN_EPS);
    a[j] = aj;
    c[j] = fmaf(-aj, m, b[j]);
    __syncthreads();
    for (int idx = j; idx < FF * HH; idx += FF) {
        int jj = idx >> 6;
        Wf[idx] = a[jj] * W[idx];
    }
    if (j < HH) {
        float acc = bias_in[j];
        for (int jj = 0; jj < FF; jj++) acc = fmaf(c[jj], W[jj * HH + j], acc);
        bf[j] = acc;
    }
}

// ---------------- h = relu(x @ Wf + bf)  [N,128] @ [128,64]
__global__ __launch_bounds__(256) void gemm_feat(const float* __restrict__ x,
                                                 const float* __restrict__ Wf,
                                                 const float* __restrict__ bf,
                                                 float* __restrict__ h, int n) {
    int lane = threadIdx.x & 63;
    int wid  = threadIdx.x >> 6;
    float w[FF];
#pragma unroll
    for (int j = 0; j < FF; j++) w[j] = Wf[j * HH + lane];
    float bv = bf[lane];
    int wstride = gridDim.x * 4;
    for (int r = blockIdx.x * 4 + wid; r < n; r += wstride) {
        float xa = x[(size_t)r * FF + lane];
        float xb = x[(size_t)r * FF + 64 + lane];
        float a0 = bv, a1 = 0.f, a2 = 0.f, a3 = 0.f;
#pragma unroll
        for (int j = 0; j < 64; j += 4) {
            a0 = fmaf(lane_bcast(xa, j),     w[j],     a0);
            a1 = fmaf(lane_bcast(xa, j + 1), w[j + 1], a1);
            a2 = fmaf(lane_bcast(xa, j + 2), w[j + 2], a2);
            a3 = fmaf(lane_bcast(xa, j + 3), w[j + 3], a3);
        }
#pragma unroll
        for (int j = 0; j < 64; j += 4) {
            a0 = fmaf(lane_bcast(xb, j),     w[64 + j],     a0);
            a1 = fmaf(lane_bcast(xb, j + 1), w[64 + j + 1], a1);
            a2 = fmaf(lane_bcast(xb, j + 2), w[64 + j + 2], a2);
            a3 = fmaf(lane_bcast(xb, j + 3), w[64 + j + 3], a3);
        }
        h[(size_t)r * HH + lane] = fmaxf((a0 + a1) + (a2 + a3), 0.f);
    }
}

// ---------------- CSR build
__global__ void hist_kernel(const int* __restrict__ dst, int* __restrict__ cnt, int e) {
    int i = blockIdx.x * blockDim.x + threadIdx.x;
    if (i < e) atomicAdd(&cnt[dst[i]], 1);
}

// --- parallel scan, 3 kernels ---
// A: per-tile (256 elems) sums, coalesced
__global__ __launch_bounds__(256) void tile_sums(const int* __restrict__ cnt,
                                                 int* __restrict__ bsum, int n) {
    __shared__ int red[256];
    int i = blockIdx.x * 256 + threadIdx.x;
    red[threadIdx.x] = (i < n) ? cnt[i] : 0;
    __syncthreads();
    for (int off = 128; off > 0; off >>= 1) {
        if (threadIdx.x < off) red[threadIdx.x] += red[threadIdx.x + off];
        __syncthreads();
    }
    if (threadIdx.x == 0) bsum[blockIdx.x] = red[0];
}

// B: exclusive scan of the <=256 tile sums (single tiny block)
__global__ __launch_bounds__(256) void scan_bsums(int* __restrict__ bsum, int nb) {
    __shared__ int s[256];
    int t = threadIdx.x;
    int v = (t < nb) ? bsum[t] : 0;
    s[t] = v;
    __syncthreads();
    for (int off = 1; off < 256; off <<= 1) {
        int x = (t >= off) ? s[t - off] : 0;
        __syncthreads();
        s[t] += x;
        __syncthreads();
    }
    if (t < nb) bsum[t] = s[t] - v;  // exclusive
}

// C: per-tile exclusive scan + tile offset -> rowptr, coalesced
__global__ __launch_bounds__(256) void scan_tiles_write(const int* __restrict__ cnt,
                                                        const int* __restrict__ bscan,
                                                        int* __restrict__ rowptr, int n) {
    __shared__ int s[256];
    int b = blockIdx.x, t = threadIdx.x;
    int i = b * 256 + t;
    int v = (i < n) ? cnt[i] : 0;
    s[t] = v;
    __syncthreads();
    for (int off = 1; off < 256; off <<= 1) {
        int x = (t >= off) ? s[t - off] : 0;
        __syncthreads();
        s[t] += x;
        __syncthreads();
    }
    if (i < n) rowptr[i] = bscan[b] + s[t] - v;
    if (b == 0 && t == 0) rowptr[n] = EE;  // all edges land in [0,N)
}

__global__ void fill_csr(const int* __restrict__ src, const int* __restrict__ dst,
                         const int* __restrict__ rowptr, int* __restrict__ cursor,
                         int* __restrict__ csr, int e) {
    int i = blockIdx.x * blockDim.x + threadIdx.x;
    if (i < e) {
        int d = dst[i];
        int slot = rowptr[d] + atomicAdd(&cursor[d], 1);
        csr[slot] = src[i];
    }
}

// ---------------- z[n] = h[n] + sum_{e in CSR[n]} h[csr_src[e]]
// Wave per node. Lane l = edge-slot (l>>4) x col-quad ((l&15)*4).
// 4 edges per float4-load instruction, 8 edges in flight in the main loop
// (latency-bound fix: was 1 serialized 4B gather per edge -> 86us/dispatch).
__global__ __launch_bounds__(256) void aggregate(const float* __restrict__ hin,
                                                 const int* __restrict__ rowptr,
                                                 const int* __restrict__ csr,
                                                 float* __restrict__ z, int n) {
    int lane  = threadIdx.x & 63;
    int wid   = threadIdx.x >> 6;
    int qcol  = (lane & 15) << 2;  // this lane's 4-col slice
    int eslot = lane >> 4;         // edge index within a 4-edge chunk
    int wstride = gridDim.x * 4;
    for (int node = blockIdx.x * 4 + wid; node < n; node += wstride) {
        int lo = rowptr[node], hi = rowptr[node + 1];
        float ax = 0.f, ay = 0.f, az = 0.f, aw = 0.f;
        int base = lo;
        for (; base + 8 <= hi; base += 8) {
            int s0 = csr[base + eslot];
            int s1 = csr[base + 4 + eslot];
            const float4 v0 = *reinterpret_cast<const float4*>(&hin[(size_t)s0 * HH + qcol]);
            const float4 v1 = *reinterpret_cast<const float4*>(&hin[(size_t)s1 * HH + qcol]);
            ax += v0.x + v1.x; ay += v0.y + v1.y;
            az += v0.z + v1.z; aw += v0.w + v1.w;
        }
        if (base + 4 <= hi) {
            int s0 = csr[base + eslot];
            const float4 v0 = *reinterpret_cast<const float4*>(&hin[(size_t)s0 * HH + qcol]);
            ax += v0.x; ay += v0.y; az += v0.z; aw += v0.w;
            base += 4;
        }
        int rem = hi - base;  // 0..3
        if (eslot < rem) {
            int s0 = csr[base + eslot];
            const float4 v0 = *reinterpret_cast<const float4*>(&hin[(size_t)s0 * HH + qcol]);
            ax += v0.x; ay += v0.y; az += v0.z; aw += v0.w;
        }
        // fold the 4 edge slots (lanes l, l^16, l^32, l^48)
        ax += __shfl_xor(ax, 16); ay += __shfl_xor(ay, 16);
        az += __shfl_xor(az, 16); aw += __shfl_xor(aw, 16);
        ax += __shfl_xor(ax, 32); ay += __shfl_xor(ay, 32);
        az += __shfl_xor(az, 32); aw += __shfl_xor(aw, 32);
        if (eslot == 0) {
            const float4 self = *reinterpret_cast<const float4*>(&hin[(size_t)node * HH + qcol]);
            float4 o;
            o.x = ax + self.x; o.y = ay + self.y;
            o.z = az + self.z; o.w = aw + self.w;
            *reinterpret_cast<float4*>(&z[(size_t)node * HH + qcol]) = o;
        }
    }
}

// ---------------- y = z @ W1 + b1 (in-place), accumulate column sum/sumsq
__global__ __launch_bounds__(256) void gin_lin1(float* __restrict__ zy,
                                                const float* __restrict__ W,
                                                const float* __restrict__ bias,
                                                float* __restrict__ stats, int n) {
    int lane = threadIdx.x & 63;
    int wid  = threadIdx.x >> 6;
    float w[HH];
#pragma unroll
    for (int j = 0; j < HH; j++) w[j] = W[j * HH + lane];
    float bv = bias[lane];
    float s = 0.f, sq = 0.f;
    int wstride = gridDim.x * 4;
    for (int r = blockIdx.x * 4 + wid; r < n; r += wstride) {
        float zv = zy[(size_t)r * HH + lane];
        float a0 = bv, a1 = 0.f;
#pragma unroll
        for (int j = 0; j < HH; j += 2) {
            a0 = fmaf(lane_bcast(zv, j),     w[j],     a0);
            a1 = fmaf(lane_bcast(zv, j + 1), w[j + 1], a1);
        }
        float acc = a0 + a1;
        zy[(size_t)r * HH + lane] = acc;
        s += acc; sq += acc * acc;
    }
    atomicAdd(&stats[lane], s);
    atomicAdd(&stats[HH + lane], sq);
}

// ---------------- a,c from stats
__global__ void bn_params(const float* __restrict__ stats, const float* __restrict__ g,
                          const float* __restrict__ b, float* __restrict__ ac,
                          float invn, int cols) {
    int k = threadIdx.x;
    if (k < cols) {
        float m = stats[k] * invn;
        float v = stats[cols + k] * invn - m * m;
        float a = g[k] * rsqrtf(v + BN_EPS);
        ac[k] = a;
        ac[cols + k] = fmaf(-a, m, b[k]);
    }
}

// ---------------- h = relu( relu(a*y+c) @ W2 + b2 ) (in-place)
__global__ __launch_bounds__(256) void gin_lin2(float* __restrict__ yh,
                                                const float* __restrict__ ac,
                                                const float* __restrict__ W2,
                                                const float* __restrict__ b2, int n) {
    int lane = threadIdx.x & 63;
    int wid  = threadIdx.x >> 6;
    float w[HH];
#pragma unroll
    for (int j = 0; j < HH; j++) w[j] = W2[j * HH + lane];
    float a = ac[lane], c = ac[HH + lane];
    float bv = b2[lane];
    int wstride = gridDim.x * 4;
    for (int r = blockIdx.x * 4 + wid; r < n; r += wstride) {
        float yv = yh[(size_t)r * HH + lane];
        float zv = fmaxf(fmaf(a, yv, c), 0.f);
        float a0 = bv, a1 = 0.f;
#pragma unroll
        for (int j = 0; j < HH; j += 2) {
            a0 = fmaf(lane_bcast(zv, j),     w[j],     a0);
            a1 = fmaf(lane_bcast(zv, j + 1), w[j + 1], a1);
        }
        yh[(size_t)r * HH + lane] = fmaxf(a0 + a1, 0.f);
    }
}

// ---------------- global_add_pool: batch is sorted; block per graph, binary search bounds
__global__ __launch_bounds__(64) void pool_kernel(const float* __restrict__ h,
                                                  const int* __restrict__ batch,
                                                  float* __restrict__ hg, int n) {
    int g = blockIdx.x;
    int lo = 0, hi = n;
    while (lo < hi) { int mid = (lo + hi) >> 1; if (batch[mid] < g) lo = mid + 1; else hi = mid; }
    int start = lo;
    lo = start; hi = n;
    while (lo < hi) { int mid = (lo + hi) >> 1; if (batch[mid] < g + 1) lo = mid + 1; else hi = mid; }
    int end = lo;
    int lane = threadIdx.x;
    float acc = 0.f;
    for (int r = start; r < end; r++) acc += h[(size_t)r * HH + lane];
    hg[g * HH + lane] = acc;
}

// ---------------- head part 1: hh = relu(bn(hg) @ lin_w + lin_b), single block
__global__ __launch_bounds__(256) void head1(const float* __restrict__ hg,
                                             const float* __restrict__ g,
                                             const float* __restrict__ b,
                                             const float* __restrict__ lw,
                                             const float* __restrict__ lb,
                                             float* __restrict__ hh) {
    __shared__ float Wt[HH * HH];  // transposed: Wt[k][j] = lw[j][k]
    __shared__ float s1[256], s2[256];
    __shared__ float aa[HH], cc[HH];
    int t = threadIdx.x;
    for (int i = t; i < HH * HH; i += 256) {
        int j = i >> 6, k = i & 63;
        Wt[k * HH + j] = lw[i];
    }
    int col = t & 63, q = t >> 6;
    float s = 0.f, sq = 0.f;
    for (int r = q; r < GG; r += 4) { float v = hg[r * HH + col]; s += v; sq += v * v; }
    s1[t] = s; s2[t] = sq;
    __syncthreads();
    if (t < HH) {
        float S = s1[t] + s1[t + 64] + s1[t + 128] + s1[t + 192];
        float Q = s2[t] + s2[t + 64] + s2[t + 128] + s2[t + 192];
        float m = S * (1.f / GG), v = Q * (1.f / GG) - m * m;
        float a = g[t] * rsqrtf(v + BN_EPS);
        aa[t] = a; cc[t] = fmaf(-a, m, b[t]);
    }
    __syncthreads();
    float rv[HH];
#pragma unroll
    for (int j = 0; j < HH; j++) rv[j] = fmaf(aa[j], hg[t * HH + j], cc[j]);
#pragma unroll 4
    for (int k = 0; k < HH; k++) {
        float acc = lb[k];
#pragma unroll
        for (int j = 0; j < HH; j++) acc = fmaf(rv[j], Wt[k * HH + j], acc);
        hh[t * HH + k] = fmaxf(acc, 0.f);
    }
}

// ---------------- head part 2: out = bn(hh) @ cls_w + cls_b, single block
__global__ __launch_bounds__(256) void head2(const float* __restrict__ hh,
                                             const float* __restrict__ g,
                                             const float* __restrict__ b,
                                             const float* __restrict__ cw,
                                             const float* __restrict__ cb,
                                             float* __restrict__ out) {
    __shared__ float s1[256], s2[256];
    __shared__ float aa[HH], cc[HH];
    __shared__ float Wc[HH * CC];
    __shared__ float cbs[CC];
    int t = threadIdx.x;
    for (int i = t; i < HH * CC; i += 256) Wc[i] = cw[i];
    if (t < CC) cbs[t] = cb[t];
    int col = t & 63, q = t >> 6;
    float s = 0.f, sq = 0.f;
    for (int r = q; r < GG; r += 4) { float v = hh[r * HH + col]; s += v; sq += v * v; }
    s1[t] = s; s2[t] = sq;
    __syncthreads();
    if (t < HH) {
        float S = s1[t] + s1[t + 64] + s1[t + 128] + s1[t + 192];
        float Q = s2[t] + s2[t + 64] + s2[t + 128] + s2[t + 192];
        float m = S * (1.f / GG), v = Q * (1.f / GG) - m * m;
        float a = g[t] * rsqrtf(v + BN_EPS);
        aa[t] = a; cc[t] = fmaf(-a, m, b[t]);
    }
    __syncthreads();
    float acc[CC];
#pragma unroll
    for (int c2 = 0; c2 < CC; c2++) acc[c2] = cbs[c2];
#pragma unroll
    for (int j = 0; j < HH; j++) {
        float v = fmaf(aa[j], hh[t * HH + j], cc[j]);
#pragma unroll
        for (int c2 = 0; c2 < CC; c2++) acc[c2] = fmaf(v, Wc[j * CC + c2], acc[c2]);
    }
#pragma unroll
    for (int c2 = 0; c2 < CC; c2++) out[t * CC + c2] = acc[c2];
}

extern "C" void kernel_launch(void* const* d_in, const int* in_sizes, int n_in,
                              void* d_out, int out_size, void* d_ws, size_t ws_size,
                              hipStream_t stream) {
    const float* x        = (const float*)d_in[0];
    const int*   ei       = (const int*)d_in[1];
    const int*   srcp     = ei;
    const int*   dstp     = ei + EE;
    const int*   batchp   = (const int*)d_in[2];
    const float* bnf_g    = (const float*)d_in[3];
    const float* bnf_b    = (const float*)d_in[4];
    const float* w_feat   = (const float*)d_in[5];
    const float* b_feat   = (const float*)d_in[6];
    const float* gin_w1   = (const float*)d_in[7];
    const float* gin_b1   = (const float*)d_in[8];
    const float* gin_bn_g = (const float*)d_in[9];
    const float* gin_bn_b = (const float*)d_in[10];
    const float* gin_w2   = (const float*)d_in[11];
    const float* gin_b2   = (const float*)d_in[12];
    const float* bn_fc_g  = (const float*)d_in[13];
    const float* bn_fc_b  = (const float*)d_in[14];
    const float* lin_w    = (const float*)d_in[15];
    const float* lin_b    = (const float*)d_in[16];
    const float* bn_h_g   = (const float*)d_in[17];
    const float* bn_h_b   = (const float*)d_in[18];
    const float* cls_w    = (const float*)d_in[19];
    const float* cls_b    = (const float*)d_in[20];
    float* out = (float*)d_out;

    // workspace layout (floats, then ints)
    float* ws   = (float*)d_ws;
    float* bufA = ws;                     // N*H
    float* bufB = bufA + (size_t)NN * HH; // N*H
    float* Wf   = bufB + (size_t)NN * HH; // F*H
    float* bff  = Wf + FF * HH;           // H
    float* stats= bff + HH;               // 2*F (also reused as 2*H)
    float* ac   = stats + 2 * FF;         // 2*H
    float* hh   = ac + 2 * HH;            // G*H
    float* hg   = hh + GG * HH;           // G*H
    int* rowptr = (int*)(hg + GG * HH);   // N+1
    int* cnt    = rowptr + (NN + 1);      // N
    int* bsum   = cnt + NN;               // NB_SCAN (tile sums for scan)
    int* csr    = bsum + NB_SCAN;         // E

    // --- bn_feat folded into linear, then h0 = relu(x @ Wf + bf)
    hipMemsetAsync(stats, 0, 2 * FF * sizeof(float), stream);
    colstats128<<<256, 256, 0, stream>>>(x, stats, NN);
    fold_feat<<<1, 128, 0, stream>>>(stats, bnf_g, bnf_b, w_feat, b_feat, Wf, bff, 1.0f / NN);
    gemm_feat<<<512, 256, 0, stream>>>(x, Wf, bff, bufA, NN);

    // --- CSR build (reused by all 3 GIN layers)
    hipMemsetAsync(cnt, 0, NN * sizeof(int), stream);
    hist_kernel<<<(EE + 255) / 256, 256, 0, stream>>>(dstp, cnt, EE);
    tile_sums<<<NB_SCAN, 256, 0, stream>>>(cnt, bsum, NN);
    scan_bsums<<<1, 256, 0, stream>>>(bsum, NB_SCAN);
    scan_tiles_write<<<NB_SCAN, 256, 0, stream>>>(cnt, bsum, rowptr, NN);
    hipMemsetAsync(cnt, 0, NN * sizeof(int), stream);
    fill_csr<<<(EE + 255) / 256, 256, 0, stream>>>(srcp, dstp, rowptr, cnt, csr, EE);

    // --- 3 GIN layers, ping-pong bufA/bufB
    float* hin = bufA;
    float* hout = bufB;
    for (int i = 0; i < 3; i++) {
        aggregate<<<2048, 256, 0, stream>>>(hin, rowptr, csr, hout, NN);
        hipMemsetAsync(stats, 0, 2 * HH * sizeof(float), stream);
        gin_lin1<<<512, 256, 0, stream>>>(hout, gin_w1 + i * HH * HH, gin_b1 + i * HH, stats, NN);
        bn_params<<<1, 64, 0, stream>>>(stats, gin_bn_g + i * HH, gin_bn_b + i * HH, ac, 1.0f / NN, HH);
        gin_lin2<<<512, 256, 0, stream>>>(hout, ac, gin_w2 + i * HH * HH, gin_b2 + i * HH, NN);
        float* tmp = hin; hin = hout; hout = tmp;
    }
    // final h is in hin

    // --- pool + head
    pool_kernel<<<GG, 64, 0, stream>>>(hin, batchp, hg, NN);
    head1<<<1, 256, 0, stream>>>(hg, bn_fc_g, bn_fc_b, lin_w, lin_b, hh);
    head2<<<1, 256, 0, stream>>>(hh, bn_h_g, bn_h_b, cls_w, cls_b, out);
}